// Round 1
// baseline (474.703 us; speedup 1.0000x reference)
//
#include <hip/hip_runtime.h>

// Problem constants (fixed by setup_inputs): z_e (16,64,64,64) f32, emb (1024,64) f32
#define NROWS   65536      // B*H*W
#define NEMB    1024
#define CDIM    64
#define HWD     4096       // H*W
#define CHW     262144     // C*H*W
#define OUT_ZQ  4194304    // B*C*H*W ; d_out: [0,4194304) z_q_st | [4194304] loss | [4194305,+65536) idx as f32
#define BETA    0.25f

// numpy pairwise_sum for n=64 contiguous f32: 8 accumulators, stride-8, then
// ((r0+r1)+(r2+r3)) + ((r4+r5)+(r6+r7)). Must match bit-exactly.
__device__ __forceinline__ float np_pairwise64(const float p[64]) {
#pragma clang fp contract(off)
    float r[8];
#pragma unroll
    for (int a = 0; a < 8; ++a) r[a] = p[a];
#pragma unroll
    for (int i = 8; i < 64; i += 8) {
#pragma unroll
        for (int a = 0; a < 8; ++a) r[a] = r[a] + p[i + a];
    }
    return ((r[0] + r[1]) + (r[2] + r[3])) + ((r[4] + r[5]) + (r[6] + r[7]));
}

// s_e[j] = np-pairwise sum of emb[j]^2
__global__ void k_se(const float* __restrict__ emb, float* __restrict__ se) {
#pragma clang fp contract(off)
    int j = blockIdx.x * 256 + threadIdx.x;
    if (j < NEMB) {
        float p[64];
#pragma unroll
        for (int c = 0; c < 64; ++c) { float v = emb[(size_t)j * 64 + c]; p[c] = v * v; }
        se[j] = np_pairwise64(p);
    }
}

__global__ __launch_bounds__(256) void k_main(
        const float* __restrict__ ze, const float* __restrict__ emb,
        const float* __restrict__ se, float* __restrict__ out,
        float* __restrict__ wsloss) {
#pragma clang fp contract(off)
    __shared__ float se_s[NEMB];
    __shared__ float dmin_s[4][64];
    __shared__ int   imin_s[4][64];
    __shared__ int   bi_s[64];
    __shared__ float red_s[256];

    const int tid  = threadIdx.x;
    const int wid  = tid >> 6;
    const int lane = tid & 63;
    const int row0 = blockIdx.x * 64;        // block owns rows [row0, row0+64)
    const int row  = row0 + lane;
    const int b    = row >> 12;              // row / (H*W); whole block is in one b
    const int hw   = row & 4095;
    const size_t zbase = (size_t)b * CHW + hw;

    // stage s_e into LDS
    for (int i = tid; i < NEMB; i += 256) se_s[i] = se[i];

    // load this lane's z row (coalesced across lanes for each c)
    float z[64];
#pragma unroll
    for (int c = 0; c < 64; ++c) z[c] = ze[zbase + (size_t)c * HWD];

    // s_z with numpy pairwise order (products rounded separately; contract off)
    float sz;
    {
        float p[64];
#pragma unroll
        for (int c = 0; c < 64; ++c) p[c] = z[c] * z[c];
        sz = np_pairwise64(p);
    }
    __syncthreads();

    // each wave scans its 256 codebook entries; j ascending, strict < => first-index ties
    float best = 3.4028235e38f;
    int   bi   = 0;
    const int j0 = wid * 256;
    for (int j = j0; j < j0 + 256; j += 2) {
        const float* __restrict__ e0 = emb + (size_t)j * 64;
        float d0 = 0.0f, d1 = 0.0f;
#pragma unroll
        for (int c = 0; c < 64; ++c) {
            d0 = fmaf(e0[c],      z[c], d0);
            d1 = fmaf(e0[64 + c], z[c], d1);
        }
        float t0 = 2.0f * d0;
        float u0 = sz - t0;
        float dist0 = u0 + se_s[j];
        float t1 = 2.0f * d1;
        float u1 = sz - t1;
        float dist1 = u1 + se_s[j + 1];
        if (dist0 < best) { best = dist0; bi = j; }
        if (dist1 < best) { best = dist1; bi = j + 1; }
    }

    dmin_s[wid][lane] = best;
    imin_s[wid][lane] = bi;
    __syncthreads();

    // merge 4 waves per row, ascending wave = ascending j, strict < keeps lowest j
    if (tid < 64) {
        float bb = dmin_s[0][lane];
        int   ii = imin_s[0][lane];
#pragma unroll
        for (int w = 1; w < 4; ++w) {
            float d = dmin_s[w][lane];
            if (d < bb) { bb = d; ii = imin_s[w][lane]; }
        }
        bi_s[lane] = ii;
        out[(size_t)OUT_ZQ + 1 + row0 + lane] = (float)ii;   // idx as f32
    }
    __syncthreads();

    // z_q_st write-back + loss partial: 4096 elements (c,r) per block
    float part = 0.0f;
#pragma unroll
    for (int rep = 0; rep < 16; ++rep) {
        int i = rep * 256 + tid;      // i = c*64 + r
        int c = i >> 6;
        int r = i & 63;
        int bj = bi_s[r];
        size_t zoff = (size_t)b * CHW + (size_t)c * HWD + (row0 & 4095) + r;
        float ev = emb[(size_t)bj * 64 + c];
        float zv = ze[zoff];
        float qmz = ev - zv;          // z_q - z_e (f32, one rounding)
        out[zoff] = zv + qmz;         // straight-through forward value
        part = part + qmz * qmz;
    }

    red_s[tid] = part;
    __syncthreads();
#pragma unroll
    for (int s = 128; s >= 1; s >>= 1) {
        if (tid < s) red_s[tid] = red_s[tid] + red_s[tid + s];
        __syncthreads();
    }
    if (tid == 0) wsloss[blockIdx.x] = red_s[0];
}

__global__ void k_loss(const float* __restrict__ wsloss, float* __restrict__ out) {
#pragma clang fp contract(off)
    __shared__ float red[256];
    int tid = threadIdx.x;
    float s = 0.0f;
    for (int i = tid; i < 1024; i += 256) s = s + wsloss[i];
    red[tid] = s;
    __syncthreads();
#pragma unroll
    for (int k = 128; k >= 1; k >>= 1) {
        if (tid < k) red[tid] = red[tid] + red[tid + k];
        __syncthreads();
    }
    if (tid == 0) {
        float mse = red[0] / 4194304.0f;
        out[OUT_ZQ] = mse + BETA * mse;   // codebook_loss + beta*commit_loss
    }
}

extern "C" void kernel_launch(void* const* d_in, const int* in_sizes, int n_in,
                              void* d_out, int out_size, void* d_ws, size_t ws_size,
                              hipStream_t stream) {
    const float* ze  = (const float*)d_in[0];
    const float* emb = (const float*)d_in[1];
    float* out    = (float*)d_out;
    float* se     = (float*)d_ws;          // 1024 floats
    float* wsloss = se + NEMB;             // 1024 floats (per-block partials)

    k_se  <<<4,    256, 0, stream>>>(emb, se);
    k_main<<<1024, 256, 0, stream>>>(ze, emb, se, out, wsloss);
    k_loss<<<1,    256, 0, stream>>>(wsloss, out);
}

// Round 3
// 160.699 us; speedup vs baseline: 2.9540x; 2.9540x over previous
//
#include <hip/hip_runtime.h>

// Problem constants (fixed by setup_inputs): z_e (16,64,64,64) f32, emb (1024,64) f32
#define NROWS   65536      // B*H*W
#define NEMB    1024
#define CDIM    64
#define HWD     4096       // H*W
#define CHW     262144     // C*H*W
#define OUT_ZQ  4194304    // d_out: [0,4194304) z_q_st | [4194304] loss | [4194305,+65536) idx as f32
#define BETA    0.25f

// numpy pairwise_sum for n=64 contiguous f32: 8 accumulators, stride-8, then
// ((r0+r1)+(r2+r3)) + ((r4+r5)+(r6+r7)). Must match bit-exactly.
__device__ __forceinline__ float np_pairwise64(const float p[64]) {
#pragma clang fp contract(off)
    float r[8];
#pragma unroll
    for (int a = 0; a < 8; ++a) r[a] = p[a];
#pragma unroll
    for (int i = 8; i < 64; i += 8) {
#pragma unroll
        for (int a = 0; a < 8; ++a) r[a] = r[a] + p[i + a];
    }
    return ((r[0] + r[1]) + (r[2] + r[3])) + ((r[4] + r[5]) + (r[6] + r[7]));
}

// s_e[j] = np-pairwise sum of emb[j]^2
__global__ void k_se(const float* __restrict__ emb, float* __restrict__ se) {
#pragma clang fp contract(off)
    int j = blockIdx.x * 256 + threadIdx.x;
    if (j < NEMB) {
        float p[64];
#pragma unroll
        for (int c = 0; c < 64; ++c) { float v = emb[(size_t)j * 64 + c]; p[c] = v * v; }
        se[j] = np_pairwise64(p);
    }
}

__global__ __launch_bounds__(256, 4) void k_main(
        const float* __restrict__ ze, const float* __restrict__ emb,
        const float* __restrict__ se, float* __restrict__ out,
        float* __restrict__ wsloss) {
#pragma clang fp contract(off)
    __shared__ float es[128 * 64];     // 32 KB codebook chunk
    __shared__ float se_s[NEMB];
    __shared__ float dmin_s[4][64];
    __shared__ int   imin_s[4][64];
    __shared__ int   bi_s[64];
    __shared__ float red_s[256];

    const int tid  = threadIdx.x;
    const int wid  = tid >> 6;
    const int lane = tid & 63;
    const int row0 = blockIdx.x * 64;        // block owns rows [row0, row0+64)
    const int row  = row0 + lane;
    const int b    = row >> 12;              // whole block lies in one batch image
    const int hw   = row & 4095;
    const size_t zbase = (size_t)b * CHW + hw;

    // stage s_e into LDS
    for (int i = tid; i < NEMB; i += 256) se_s[i] = se[i];

    // this lane's z row (coalesced across lanes for each c)
    float z[64];
#pragma unroll
    for (int c = 0; c < 64; ++c) z[c] = ze[zbase + (size_t)c * HWD];

    // s_z with numpy pairwise order
    float sz;
    {
        float p[64];
#pragma unroll
        for (int c = 0; c < 64; ++c) p[c] = z[c] * z[c];
        sz = np_pairwise64(p);
    }

    float best = 3.4028235e38f;
    int   bi   = 0;

    // 8 chunks of 128 codebook entries; wave w scans 32 entries per chunk.
    // Wave w's global-j sequence is ascending, so strict < keeps its lowest j.
    for (int ch = 0; ch < 8; ++ch) {
        __syncthreads();   // previous chunk fully consumed
        // cooperative stage: 128 entries x 64 f32 = 2048 float4, 8 per thread
        {
            const float4* __restrict__ src =
                (const float4*)(emb + (size_t)ch * 128 * 64);
            float4* dst = (float4*)es;
#pragma unroll
            for (int r = 0; r < 8; ++r) dst[r * 256 + tid] = src[r * 256 + tid];
        }
        __syncthreads();

        const int jbase = ch * 128 + wid * 32;
        const float* __restrict__ ew = es + wid * 32 * 64;
#pragma unroll 2
        for (int jl = 0; jl < 32; jl += 4) {
            const float* __restrict__ e0 = ew + jl * 64;
            float d0 = 0.0f, d1 = 0.0f, d2 = 0.0f, d3 = 0.0f;
#pragma unroll
            for (int c4 = 0; c4 < 16; ++c4) {
                const float4 a0 = *(const float4*)(e0 + c4 * 4);
                const float4 a1 = *(const float4*)(e0 + 64 + c4 * 4);
                const float4 a2 = *(const float4*)(e0 + 128 + c4 * 4);
                const float4 a3 = *(const float4*)(e0 + 192 + c4 * 4);
                const int c = c4 * 4;
                d0 = fmaf(a0.x, z[c], d0); d0 = fmaf(a0.y, z[c+1], d0);
                d0 = fmaf(a0.z, z[c+2], d0); d0 = fmaf(a0.w, z[c+3], d0);
                d1 = fmaf(a1.x, z[c], d1); d1 = fmaf(a1.y, z[c+1], d1);
                d1 = fmaf(a1.z, z[c+2], d1); d1 = fmaf(a1.w, z[c+3], d1);
                d2 = fmaf(a2.x, z[c], d2); d2 = fmaf(a2.y, z[c+1], d2);
                d2 = fmaf(a2.z, z[c+2], d2); d2 = fmaf(a2.w, z[c+3], d2);
                d3 = fmaf(a3.x, z[c], d3); d3 = fmaf(a3.y, z[c+1], d3);
                d3 = fmaf(a3.z, z[c+2], d3); d3 = fmaf(a3.w, z[c+3], d3);
            }
            const int j = jbase + jl;
            const float dist0 = (sz - 2.0f * d0) + se_s[j];
            const float dist1 = (sz - 2.0f * d1) + se_s[j + 1];
            const float dist2 = (sz - 2.0f * d2) + se_s[j + 2];
            const float dist3 = (sz - 2.0f * d3) + se_s[j + 3];
            if (dist0 < best) { best = dist0; bi = j; }
            if (dist1 < best) { best = dist1; bi = j + 1; }
            if (dist2 < best) { best = dist2; bi = j + 2; }
            if (dist3 < best) { best = dist3; bi = j + 3; }
        }
    }

    dmin_s[wid][lane] = best;
    imin_s[wid][lane] = bi;
    __syncthreads();

    // waves hold interleaved j-subsets -> lexicographic (dist, idx) merge
    // reproduces numpy's global first-index tie rule.
    if (tid < 64) {
        float bb = dmin_s[0][lane];
        int   ii = imin_s[0][lane];
#pragma unroll
        for (int w = 1; w < 4; ++w) {
            float d = dmin_s[w][lane];
            int   i2 = imin_s[w][lane];
            if (d < bb || (d == bb && i2 < ii)) { bb = d; ii = i2; }
        }
        bi_s[lane] = ii;
        out[(size_t)OUT_ZQ + 1 + row0 + lane] = (float)ii;   // idx as f32
    }
    __syncthreads();

    // z_q_st write-back + loss partial: 4096 elements (c,r) per block
    float part = 0.0f;
#pragma unroll
    for (int rep = 0; rep < 16; ++rep) {
        int i = rep * 256 + tid;      // i = c*64 + r
        int c = i >> 6;
        int r = i & 63;
        int bj = bi_s[r];
        size_t zoff = (size_t)b * CHW + (size_t)c * HWD + (row0 & 4095) + r;
        float ev = emb[(size_t)bj * 64 + c];
        float zv = ze[zoff];
        float qmz = ev - zv;          // z_q - z_e (f32, one rounding)
        out[zoff] = zv + qmz;         // straight-through forward value
        part = part + qmz * qmz;
    }

    red_s[tid] = part;
    __syncthreads();
#pragma unroll
    for (int s = 128; s >= 1; s >>= 1) {
        if (tid < s) red_s[tid] = red_s[tid] + red_s[tid + s];
        __syncthreads();
    }
    if (tid == 0) wsloss[blockIdx.x] = red_s[0];
}

__global__ void k_loss(const float* __restrict__ wsloss, float* __restrict__ out) {
#pragma clang fp contract(off)
    __shared__ float red[256];
    int tid = threadIdx.x;
    float s = 0.0f;
    for (int i = tid; i < 1024; i += 256) s = s + wsloss[i];
    red[tid] = s;
    __syncthreads();
#pragma unroll
    for (int k = 128; k >= 1; k >>= 1) {
        if (tid < k) red[tid] = red[tid] + red[tid + k];
        __syncthreads();
    }
    if (tid == 0) {
        float mse = red[0] / 4194304.0f;
        out[OUT_ZQ] = mse + BETA * mse;   // codebook_loss + beta*commit_loss
    }
}

extern "C" void kernel_launch(void* const* d_in, const int* in_sizes, int n_in,
                              void* d_out, int out_size, void* d_ws, size_t ws_size,
                              hipStream_t stream) {
    const float* ze  = (const float*)d_in[0];
    const float* emb = (const float*)d_in[1];
    float* out    = (float*)d_out;
    float* se     = (float*)d_ws;          // 1024 floats
    float* wsloss = se + NEMB;             // 1024 floats

    k_se  <<<4,    256, 0, stream>>>(emb, se);
    k_main<<<1024, 256, 0, stream>>>(ze, emb, se, out, wsloss);
    k_loss<<<1,    256, 0, stream>>>(wsloss, out);
}

// Round 4
// 160.548 us; speedup vs baseline: 2.9568x; 1.0009x over previous
//
#include <hip/hip_runtime.h>

// Problem constants (fixed by setup_inputs): z_e (16,64,64,64) f32, emb (1024,64) f32
#define NROWS   65536      // B*H*W
#define NEMB    1024
#define CDIM    64
#define HWD     4096       // H*W
#define CHW     262144     // C*H*W
#define OUT_ZQ  4194304    // d_out: [0,4194304) z_q_st | [4194304] loss | [4194305,+65536) idx as f32
#define BETA    0.25f

// numpy pairwise_sum for n=64 contiguous f32: 8 accumulators, stride-8, then
// ((r0+r1)+(r2+r3)) + ((r4+r5)+(r6+r7)). Must match bit-exactly.
__device__ __forceinline__ float np_pairwise64(const float p[64]) {
#pragma clang fp contract(off)
    float r[8];
#pragma unroll
    for (int a = 0; a < 8; ++a) r[a] = p[a];
#pragma unroll
    for (int i = 8; i < 64; i += 8) {
#pragma unroll
        for (int a = 0; a < 8; ++a) r[a] = r[a] + p[i + a];
    }
    return ((r[0] + r[1]) + (r[2] + r[3])) + ((r[4] + r[5]) + (r[6] + r[7]));
}

// s_e[j] = np-pairwise sum of emb[j]^2
__global__ void k_se(const float* __restrict__ emb, float* __restrict__ se) {
#pragma clang fp contract(off)
    int j = blockIdx.x * 256 + threadIdx.x;
    if (j < NEMB) {
        float p[64];
#pragma unroll
        for (int c = 0; c < 64; ++c) { float v = emb[(size_t)j * 64 + c]; p[c] = v * v; }
        se[j] = np_pairwise64(p);
    }
}

// launch_bounds(256, 2): VGPR cap 256 so z[64] stays in registers (round-3's
// (256,4) capped at 128 and the compiler chose 64 -> z[] spilled to scratch,
// VALU 2.5x the FMA floor).
__global__ __launch_bounds__(256, 2) void k_main(
        const float* __restrict__ ze, const float* __restrict__ emb,
        const float* __restrict__ se, float* __restrict__ out,
        float* __restrict__ wsloss) {
#pragma clang fp contract(off)
    __shared__ float es[128 * 64];     // 32 KB codebook chunk
    __shared__ float se_s[NEMB];
    __shared__ float dmin_s[4][64];
    __shared__ int   imin_s[4][64];
    __shared__ int   bi_s[64];
    __shared__ float red_s[256];

    const int tid  = threadIdx.x;
    const int wid  = tid >> 6;
    const int lane = tid & 63;
    const int row0 = blockIdx.x * 64;        // block owns rows [row0, row0+64)
    const int row  = row0 + lane;
    const int b    = row >> 12;              // whole block lies in one batch image
    const int hw   = row & 4095;
    const size_t zbase = (size_t)b * CHW + hw;

    // stage s_e into LDS
    for (int i = tid; i < NEMB; i += 256) se_s[i] = se[i];

    // this lane's z row (coalesced across lanes for each c)
    float z[64];
#pragma unroll
    for (int c = 0; c < 64; ++c) z[c] = ze[zbase + (size_t)c * HWD];

    // s_z with numpy pairwise order
    float sz;
    {
        float p[64];
#pragma unroll
        for (int c = 0; c < 64; ++c) p[c] = z[c] * z[c];
        sz = np_pairwise64(p);
    }

    float best = 3.4028235e38f;
    int   bi   = 0;

    // 8 chunks of 128 codebook entries; wave w scans 32 entries per chunk.
    // Wave w's global-j sequence is ascending, so strict < keeps its lowest j.
    for (int ch = 0; ch < 8; ++ch) {
        __syncthreads();   // previous chunk fully consumed
        // cooperative stage: 128 entries x 64 f32 = 2048 float4, 8 per thread
        {
            const float4* __restrict__ src =
                (const float4*)(emb + (size_t)ch * 128 * 64);
            float4* dst = (float4*)es;
#pragma unroll
            for (int r = 0; r < 8; ++r) dst[r * 256 + tid] = src[r * 256 + tid];
        }
        __syncthreads();

        const int jbase = ch * 128 + wid * 32;
        const float* __restrict__ ew = es + wid * 32 * 64;
#pragma unroll 2
        for (int jl = 0; jl < 32; jl += 4) {
            const float* __restrict__ e0 = ew + jl * 64;
            float d0 = 0.0f, d1 = 0.0f, d2 = 0.0f, d3 = 0.0f;
#pragma unroll
            for (int c4 = 0; c4 < 16; ++c4) {
                const float4 a0 = *(const float4*)(e0 + c4 * 4);
                const float4 a1 = *(const float4*)(e0 + 64 + c4 * 4);
                const float4 a2 = *(const float4*)(e0 + 128 + c4 * 4);
                const float4 a3 = *(const float4*)(e0 + 192 + c4 * 4);
                const int c = c4 * 4;
                d0 = fmaf(a0.x, z[c], d0); d0 = fmaf(a0.y, z[c+1], d0);
                d0 = fmaf(a0.z, z[c+2], d0); d0 = fmaf(a0.w, z[c+3], d0);
                d1 = fmaf(a1.x, z[c], d1); d1 = fmaf(a1.y, z[c+1], d1);
                d1 = fmaf(a1.z, z[c+2], d1); d1 = fmaf(a1.w, z[c+3], d1);
                d2 = fmaf(a2.x, z[c], d2); d2 = fmaf(a2.y, z[c+1], d2);
                d2 = fmaf(a2.z, z[c+2], d2); d2 = fmaf(a2.w, z[c+3], d2);
                d3 = fmaf(a3.x, z[c], d3); d3 = fmaf(a3.y, z[c+1], d3);
                d3 = fmaf(a3.z, z[c+2], d3); d3 = fmaf(a3.w, z[c+3], d3);
            }
            const int j = jbase + jl;
            const float dist0 = (sz - 2.0f * d0) + se_s[j];
            const float dist1 = (sz - 2.0f * d1) + se_s[j + 1];
            const float dist2 = (sz - 2.0f * d2) + se_s[j + 2];
            const float dist3 = (sz - 2.0f * d3) + se_s[j + 3];
            if (dist0 < best) { best = dist0; bi = j; }
            if (dist1 < best) { best = dist1; bi = j + 1; }
            if (dist2 < best) { best = dist2; bi = j + 2; }
            if (dist3 < best) { best = dist3; bi = j + 3; }
        }
    }

    dmin_s[wid][lane] = best;
    imin_s[wid][lane] = bi;
    __syncthreads();

    // waves hold interleaved j-subsets -> lexicographic (dist, idx) merge
    // reproduces numpy's global first-index tie rule.
    if (tid < 64) {
        float bb = dmin_s[0][lane];
        int   ii = imin_s[0][lane];
#pragma unroll
        for (int w = 1; w < 4; ++w) {
            float d = dmin_s[w][lane];
            int   i2 = imin_s[w][lane];
            if (d < bb || (d == bb && i2 < ii)) { bb = d; ii = i2; }
        }
        bi_s[lane] = ii;
        out[(size_t)OUT_ZQ + 1 + row0 + lane] = (float)ii;   // idx as f32
    }
    __syncthreads();

    // z_q_st write-back + loss partial: 4096 elements (c,r) per block
    float part = 0.0f;
#pragma unroll
    for (int rep = 0; rep < 16; ++rep) {
        int i = rep * 256 + tid;      // i = c*64 + r
        int c = i >> 6;
        int r = i & 63;
        int bj = bi_s[r];
        size_t zoff = (size_t)b * CHW + (size_t)c * HWD + (row0 & 4095) + r;
        float ev = emb[(size_t)bj * 64 + c];
        float zv = ze[zoff];
        float qmz = ev - zv;          // z_q - z_e (f32, one rounding)
        out[zoff] = zv + qmz;         // straight-through forward value
        part = part + qmz * qmz;
    }

    red_s[tid] = part;
    __syncthreads();
#pragma unroll
    for (int s = 128; s >= 1; s >>= 1) {
        if (tid < s) red_s[tid] = red_s[tid] + red_s[tid + s];
        __syncthreads();
    }
    if (tid == 0) wsloss[blockIdx.x] = red_s[0];
}

__global__ void k_loss(const float* __restrict__ wsloss, float* __restrict__ out) {
#pragma clang fp contract(off)
    __shared__ float red[256];
    int tid = threadIdx.x;
    float s = 0.0f;
    for (int i = tid; i < 1024; i += 256) s = s + wsloss[i];
    red[tid] = s;
    __syncthreads();
#pragma unroll
    for (int k = 128; k >= 1; k >>= 1) {
        if (tid < k) red[tid] = red[tid] + red[tid + k];
        __syncthreads();
    }
    if (tid == 0) {
        float mse = red[0] / 4194304.0f;
        out[OUT_ZQ] = mse + BETA * mse;   // codebook_loss + beta*commit_loss
    }
}

extern "C" void kernel_launch(void* const* d_in, const int* in_sizes, int n_in,
                              void* d_out, int out_size, void* d_ws, size_t ws_size,
                              hipStream_t stream) {
    const float* ze  = (const float*)d_in[0];
    const float* emb = (const float*)d_in[1];
    float* out    = (float*)d_out;
    float* se     = (float*)d_ws;          // 1024 floats
    float* wsloss = se + NEMB;             // 1024 floats

    k_se  <<<4,    256, 0, stream>>>(emb, se);
    k_main<<<1024, 256, 0, stream>>>(ze, emb, se, out, wsloss);
    k_loss<<<1,    256, 0, stream>>>(wsloss, out);
}

// Round 5
// 143.343 us; speedup vs baseline: 3.3117x; 1.1200x over previous
//
#include <hip/hip_runtime.h>

// Problem constants: z_e (16,64,64,64) f32, emb (1024,64) f32
#define NROWS   65536      // B*H*W
#define NEMB    1024
#define CDIM    64
#define HWD     4096       // H*W
#define CHW     262144     // C*H*W
#define OUT_ZQ  4194304    // d_out: [0,4194304) z_q_st | [4194304] loss | [4194305,+65536) idx as f32
#define BETA    0.25f

// compile-time float4 component select (folds under full unroll)
#define F4C(v,i) ((i)==0?(v).x:((i)==1?(v).y:((i)==2?(v).z:(v).w)))

// numpy pairwise_sum for n=64 contiguous f32: 8 accumulators, stride-8, then
// ((r0+r1)+(r2+r3)) + ((r4+r5)+(r6+r7)). Must match bit-exactly.
__device__ __forceinline__ float np_pairwise64(const float p[64]) {
#pragma clang fp contract(off)
    float r[8];
#pragma unroll
    for (int a = 0; a < 8; ++a) r[a] = p[a];
#pragma unroll
    for (int i = 8; i < 64; i += 8) {
#pragma unroll
        for (int a = 0; a < 8; ++a) r[a] = r[a] + p[i + a];
    }
    return ((r[0] + r[1]) + (r[2] + r[3])) + ((r[4] + r[5]) + (r[6] + r[7]));
}

__global__ void k_se(const float* __restrict__ emb, float* __restrict__ se) {
#pragma clang fp contract(off)
    int j = blockIdx.x * 256 + threadIdx.x;
    if (j < NEMB) {
        float p[64];
#pragma unroll
        for (int c = 0; c < 64; ++c) { float v = emb[(size_t)j * 64 + c]; p[c] = v * v; }
        se[j] = np_pairwise64(p);
    }
}

// Register-tiled LDS GEMM: thread = 4 rows x 4 entries (16 acc), operands from
// LDS (zt transposed z, es swizzled codebook chunk). No per-thread z[64] array
// -> no scratch (rounds 3/4: compiler pinned VGPR=64 and spilled z[]).
__global__ __launch_bounds__(256, 4) void k_main(
        const float* __restrict__ ze, const float* __restrict__ emb,
        const float* __restrict__ se, float* __restrict__ out,
        float* __restrict__ wsloss) {
#pragma clang fp contract(off)
    __shared__ float zt[4096];     // zt[c*64 + r] : z transposed, 16 KB
    __shared__ float es[4096];     // 64-entry chunk, float4-slot swizzled, 16 KB
    __shared__ float se_s[NEMB];   // 4 KB
    __shared__ float sz_s[64];
    __shared__ int   bi_s[64];

    const int tid  = threadIdx.x;
    const int rg   = tid & 15;     // row-group: rows 4rg..4rg+3
    const int eg   = tid >> 4;     // entry-group within chunk: entries 4eg..4eg+3
    const int row0 = blockIdx.x * 64;
    const int b    = row0 >> 12;   // whole block lies in one batch image
    const int hw0  = row0 & 4095;  // 64-aligned
    const float* __restrict__ zblk = ze + (size_t)b * CHW + hw0;

    // stage s_e
#pragma unroll
    for (int k = 0; k < 4; ++k) se_s[k * 256 + tid] = se[k * 256 + tid];

    // stage z transposed: idx = c*64 + r ; per-wave reads are 256B coalesced,
    // LDS writes consecutive (conflict-free)
#pragma unroll
    for (int k = 0; k < 16; ++k) {
        int idx = k * 256 + tid;
        int c = idx >> 6, r = idx & 63;
        zt[idx] = zblk[(size_t)c * HWD + r];
    }
    __syncthreads();

    // sz per row, numpy pairwise order (bit-exact; z values identical via LDS)
    if (tid < 64) {
        float p[64];
#pragma unroll
        for (int c = 0; c < 64; ++c) { float v = zt[c * 64 + tid]; p[c] = v * v; }
        sz_s[tid] = np_pairwise64(p);
    }
    __syncthreads();

    const float4 sz4 = *(const float4*)&sz_s[rg * 4];

    float best[4] = {3.4028235e38f, 3.4028235e38f, 3.4028235e38f, 3.4028235e38f};
    int   bi[4]   = {0, 0, 0, 0};

    // 16 chunks x 64 entries; thread's j = ch*64 + eg*4 + jj (ascending in ch)
    for (int ch = 0; ch < 16; ++ch) {
        __syncthreads();   // previous chunk fully consumed
        {
            const float4* __restrict__ src = (const float4*)(emb + ch * 4096);
#pragma unroll
            for (int k = 0; k < 4; ++k) {
                int idx = k * 256 + tid;          // float4 index: (jl, c4)
                int jl = idx >> 4, c4 = idx & 15;
                *(float4*)&es[(jl << 6) + ((c4 ^ (jl & 15)) << 2)] = src[idx];
            }
        }
        __syncthreads();

        const float4 se4 = *(const float4*)&se_s[ch * 64 + eg * 4];
        float acc[4][4];
#pragma unroll
        for (int a = 0; a < 4; ++a)
#pragma unroll
            for (int q = 0; q < 4; ++q) acc[a][q] = 0.0f;

#pragma unroll 4
        for (int c4 = 0; c4 < 16; ++c4) {
            float4 zq[4], ef[4];
#pragma unroll
            for (int cc = 0; cc < 4; ++cc)
                zq[cc] = *(const float4*)&zt[((c4 * 4 + cc) << 6) + (rg << 2)];
#pragma unroll
            for (int jj = 0; jj < 4; ++jj) {
                int jl = eg * 4 + jj;
                ef[jj] = *(const float4*)&es[(jl << 6) + ((c4 ^ (jl & 15)) << 2)];
            }
            // c ascending (cc outer) keeps each (row,entry) fmaf chain in the
            // exact order of rounds 3/4 -> bit-identical dist
#pragma unroll
            for (int cc = 0; cc < 4; ++cc)
#pragma unroll
                for (int jj = 0; jj < 4; ++jj)
#pragma unroll
                    for (int rr = 0; rr < 4; ++rr)
                        acc[jj][rr] = fmaf(F4C(ef[jj], cc), F4C(zq[cc], rr), acc[jj][rr]);
        }

        const int j0 = ch * 64 + eg * 4;
#pragma unroll
        for (int jj = 0; jj < 4; ++jj) {
            float sej = F4C(se4, jj);
#pragma unroll
            for (int rr = 0; rr < 4; ++rr) {
                float dist = (F4C(sz4, rr) - 2.0f * acc[jj][rr]) + sej;
                if (dist < best[rr]) { best[rr] = dist; bi[rr] = j0 + jj; }
            }
        }
    }

    // merge: overlay scratch LDS on zt/es (dead after main loop)
    __syncthreads();
    float* dmin_s = zt;          // 1024 floats
    int*   imin_s = (int*)es;    // 1024 ints
#pragma unroll
    for (int rr = 0; rr < 4; ++rr) {
        dmin_s[tid * 4 + rr] = best[rr];
        imin_s[tid * 4 + rr] = bi[rr];
    }
    __syncthreads();

    // row r: contributors are threads t = m*16 + (r>>2) at slot (r&3).
    // lexicographic (dist, idx) min == numpy global first-index argmin.
    if (tid < 64) {
        int rgm = tid >> 2, rrm = tid & 3;
        float bb = 3.4028235e38f; int ii = 0x7fffffff;
#pragma unroll
        for (int m = 0; m < 16; ++m) {
            int t = m * 16 + rgm;
            float d  = dmin_s[t * 4 + rrm];
            int   i2 = imin_s[t * 4 + rrm];
            if (d < bb || (d == bb && i2 < ii)) { bb = d; ii = i2; }
        }
        bi_s[tid] = ii;
        out[(size_t)OUT_ZQ + 1 + row0 + tid] = (float)ii;   // idx as f32
    }
    __syncthreads();

    // z_q_st write-back + loss partial: 4096 elements (c,r) per block
    float part = 0.0f;
#pragma unroll
    for (int rep = 0; rep < 16; ++rep) {
        int i = rep * 256 + tid;
        int c = i >> 6, r = i & 63;
        int bj = bi_s[r];
        size_t zoff = (size_t)b * CHW + (size_t)c * HWD + hw0 + r;
        float ev = emb[(size_t)bj * 64 + c];
        float zv = ze[zoff];
        float qmz = ev - zv;      // z_q - z_e (f32, one rounding)
        out[zoff] = zv + qmz;     // straight-through forward value
        part = part + qmz * qmz;
    }

    float* red_s = zt;   // dmin region dead after merge sync
    red_s[tid] = part;
    __syncthreads();
#pragma unroll
    for (int s = 128; s >= 1; s >>= 1) {
        if (tid < s) red_s[tid] = red_s[tid] + red_s[tid + s];
        __syncthreads();
    }
    if (tid == 0) wsloss[blockIdx.x] = red_s[0];
}

__global__ void k_loss(const float* __restrict__ wsloss, float* __restrict__ out) {
#pragma clang fp contract(off)
    __shared__ float red[256];
    int tid = threadIdx.x;
    float s = 0.0f;
    for (int i = tid; i < 1024; i += 256) s = s + wsloss[i];
    red[tid] = s;
    __syncthreads();
#pragma unroll
    for (int k = 128; k >= 1; k >>= 1) {
        if (tid < k) red[tid] = red[tid] + red[tid + k];
        __syncthreads();
    }
    if (tid == 0) {
        float mse = red[0] / 4194304.0f;
        out[OUT_ZQ] = mse + BETA * mse;   // codebook_loss + beta*commit_loss
    }
}

extern "C" void kernel_launch(void* const* d_in, const int* in_sizes, int n_in,
                              void* d_out, int out_size, void* d_ws, size_t ws_size,
                              hipStream_t stream) {
    const float* ze  = (const float*)d_in[0];
    const float* emb = (const float*)d_in[1];
    float* out    = (float*)d_out;
    float* se     = (float*)d_ws;          // 1024 floats
    float* wsloss = se + NEMB;             // 1024 floats

    k_se  <<<4,    256, 0, stream>>>(emb, se);
    k_main<<<1024, 256, 0, stream>>>(ze, emb, se, out, wsloss);
    k_loss<<<1,    256, 0, stream>>>(wsloss, out);
}